// Round 6
// baseline (599.814 us; speedup 1.0000x reference)
//
#include <hip/hip_runtime.h>
#include <math.h>

#define BB 32
#define HH 512
#define WW 512
#define NB 4096                      // 64*64 blocks per image
#define QD 25165824                  // 32*3*4096*64  (qdct elements)
#define PP 16777216                  // 32*512*512*2  (enc_qf elements)
#define TAILOFF (2 * (size_t)QD + 2 * (size_t)PP)  // 83886080

// compile-time zigzag (folds to literal register selects in unrolled loops)
constexpr int ZZc[64] = {
    0,1,8,16,9,2,3,10,17,24,32,25,18,11,4,5,12,19,26,33,40,48,41,34,27,20,13,6,
    7,14,21,28,35,42,49,56,57,50,43,36,29,22,15,23,30,37,44,51,58,59,52,45,38,31,
    39,46,53,60,61,54,47,55,62,63};
__constant__ int c_zz[64] = {
    0,1,8,16,9,2,3,10,17,24,32,25,18,11,4,5,12,19,26,33,40,48,41,34,27,20,13,6,
    7,14,21,28,35,42,49,56,57,50,43,36,29,22,15,23,30,37,44,51,58,59,52,45,38,31,
    39,46,53,60,61,54,47,55,62,63};

struct QArg { float Cf[64]; double rqY[64]; double rqC[64]; };

__device__ __forceinline__ double qf_from_rank(double r) {
    double q = rint(2.0 + r * 48.0 + 0.0);
    return fmin(fmax(q, 2.0), 50.0);
}
__device__ __forceinline__ double scale_from_qf(double qf) {
    double s = (qf < 50.0) ? (5000.0 / qf) : (200.0 - 2.0 * qf);
    return rint(s) / 100.0;
}

// Rounded YCbCr for 16 consecutive px of one row; identical fp64 rint math to R1-R4.
__device__ __forceinline__ void ycc16(const float* __restrict__ src, int p0,
                                      int* y, int* cb, int* cr) {
    float px[48];
    const float4* s4 = (const float4*)(src + (size_t)p0 * 3);
    #pragma unroll
    for (int k = 0; k < 12; ++k) ((float4*)px)[k] = s4[k];
    #pragma unroll
    for (int k = 0; k < 16; ++k) {
        double R = px[3 * k], G = px[3 * k + 1], Bv = px[3 * k + 2];
        y[k]  = (int)(rint(R * (double)0.299f     + G * (double)0.587f     + Bv * (double)0.114f)             - 128.0);
        cb[k] = (int)(rint(R * (double)-0.168736f + G * (double)-0.331264f + Bv * (double)0.5f       + 128.0) - 128.0);
        cr[k] = (int)(rint(R * (double)0.5f       + G * (double)-0.418688f + Bv * (double)-0.081312f + 128.0) - 128.0);
    }
}

// Energy via Parseval: sum d^2 == sum x^2 (orthonormal DCT), d00 == sum(x)/8.
__global__ __launch_bounds__(256, 4) void k_energy(const float* __restrict__ rgb,
                                                   double* __restrict__ ey,
                                                   double* __restrict__ ec) {
    __shared__ int4 part[3][8][32];
    __shared__ double ecomb[2][64];
    int b = blockIdx.x >> 6, i = blockIdx.x & 63, t = threadIdx.x;
    const float* src = rgb + (size_t)(b * HH + i * 8) * WW * 3;
    {
        int y[16], cb[16], cr[16];
        ycc16(src, t * 16, y, cb, cr);
        int s[3][2] = {{0,0},{0,0},{0,0}}, s2[3][2] = {{0,0},{0,0},{0,0}};
        #pragma unroll
        for (int k = 0; k < 16; ++k) {
            int h = k >> 3;
            s[0][h] += y[k];  s2[0][h] += y[k] * y[k];
            s[1][h] += cb[k]; s2[1][h] += cb[k] * cb[k];
            s[2][h] += cr[k]; s2[2][h] += cr[k] * cr[k];
        }
        int r0 = t >> 5, c = t & 31;
        #pragma unroll
        for (int ch = 0; ch < 3; ++ch)
            part[ch][r0][c] = make_int4(s[ch][0], s2[ch][0], s[ch][1], s2[ch][1]);
    }
    __syncthreads();
    int ch = t >> 6, j = t & 63;
    if (ch < 3) {
        int S = 0, S2 = 0;
        #pragma unroll
        for (int r = 0; r < 8; ++r) {
            const int2* p = (const int2*)&part[ch][r][j >> 1];
            int2 v = p[j & 1];
            S += v.x; S2 += v.y;
        }
        double e = log1p((double)S2 - (double)S * (double)S * (1.0 / 64.0) + 1e-6);
        if (ch == 0) ey[b * NB + i * 64 + j] = e;
        else ecomb[ch - 1][j] = e;
    }
    __syncthreads();
    if (t < 64) ec[b * NB + i * 64 + t] = 0.5 * (ecomb[0][t] + ecomb[1][t]);
}

__global__ __launch_bounds__(256) void k_minmax(const double* __restrict__ ey,
                                                const double* __restrict__ ec,
                                                double* __restrict__ mm,
                                                float* __restrict__ out_tail) {
    __shared__ double s0[256], s1[256], s2[256], s3[256];
    int b = blockIdx.x, tid = threadIdx.x;
    double mny = 1e300, mxy = -1e300, mnc = 1e300, mxc = -1e300;
    for (int n = tid; n < NB; n += 256) {
        double vy = ey[b * NB + n], vc = ec[b * NB + n];
        mny = fmin(mny, vy); mxy = fmax(mxy, vy);
        mnc = fmin(mnc, vc); mxc = fmax(mxc, vc);
    }
    s0[tid] = mny; s1[tid] = mxy; s2[tid] = mnc; s3[tid] = mxc;
    __syncthreads();
    for (int off = 128; off > 0; off >>= 1) {
        if (tid < off) {
            s0[tid] = fmin(s0[tid], s0[tid + off]);
            s1[tid] = fmax(s1[tid], s1[tid + off]);
            s2[tid] = fmin(s2[tid], s2[tid + off]);
            s3[tid] = fmax(s3[tid], s3[tid + off]);
        }
        __syncthreads();
    }
    if (tid == 0) {
        mm[b] = s0[0]; mm[32 + b] = s1[0]; mm[64 + b] = s2[0]; mm[96 + b] = s3[0];
        double ry = (s1[0] - s0[0]) / (s1[0] - s0[0] + 1e-6);
        double rc = (s3[0] - s2[0]) / (s3[0] - s2[0] + 1e-6);
        out_tail[b]      = (float)qf_from_rank(0.0);
        out_tail[32 + b] = (float)qf_from_rank(ry);
        out_tail[64 + b] = (float)qf_from_rank(0.0);
        out_tail[96 + b] = (float)qf_from_rank(rc);
    }
}

// int16 LDS staging -> fp32 DCT -> fp64-rint quantize (R4-bit-identical) ->
// qdct + blocks from REGISTERS (prev block via __shfl_up; no sq LDS round-trip).
__global__ __launch_bounds__(256, 4) void k_quant(const float* __restrict__ rgb,
                                                  QArg A,
                                                  const double* __restrict__ ey,
                                                  const double* __restrict__ ec,
                                                  const double* __restrict__ mm,
                                                  float* __restrict__ out) {
    __shared__ __align__(16) short sm[12288];   // ycc planes [3][8][512]
    int b = blockIdx.x >> 6, i = blockIdx.x & 63, t = threadIdx.x;
    {
        int y[16], cb[16], cr[16];
        ycc16(rgb + (size_t)(b * HH + i * 8) * WW * 3, t * 16, y, cb, cr);
        alignas(16) short yb[16], cbb[16], crb[16];
        #pragma unroll
        for (int k = 0; k < 16; ++k) {
            yb[k] = (short)y[k]; cbb[k] = (short)cb[k]; crb[k] = (short)cr[k];
        }
        int4* d0 = (int4*)&sm[0 * 4096 + 16 * t];
        int4* d1 = (int4*)&sm[1 * 4096 + 16 * t];
        int4* d2 = (int4*)&sm[2 * 4096 + 16 * t];
        d0[0] = ((int4*)yb)[0];  d0[1] = ((int4*)yb)[1];
        d1[0] = ((int4*)cbb)[0]; d1[1] = ((int4*)cbb)[1];
        d2[0] = ((int4*)crb)[0]; d2[1] = ((int4*)crb)[1];
    }
    __syncthreads();
    int ch = t >> 6, j = t & 63;
    if (ch < 3) {
        // decision math (fp64, identical to R1-R4)
        int gt = b * NB + i * 64 + j;
        double eyv = ey[gt], ecv = ec[gt];
        double mny = mm[b], mxy = mm[32 + b], mnc = mm[64 + b], mxc = mm[96 + b];
        double ry = (eyv - mny) / (mxy - mny + 1e-6);
        double rc = (ecv - mnc) / (mxc - mnc + 1e-6);
        double qy = qf_from_rank(ry), qc = qf_from_rank(rc);
        double sy = scale_from_qf(qy), sc = scale_from_qf(qc);

        // fp32 DCT row pass
        float U[8][8];
        #pragma unroll
        for (int r = 0; r < 8; ++r) {
            alignas(16) short xs[8];
            *(int4*)xs = *(const int4*)&sm[ch * 4096 + r * 512 + j * 8];
            float xr[8];
            #pragma unroll
            for (int s = 0; s < 8; ++s) xr[s] = (float)xs[s];
            #pragma unroll
            for (int v = 0; v < 8; ++v) {
                float u = 0.0f;
                #pragma unroll
                for (int s = 0; s < 8; ++s) u += xr[s] * A.Cf[v * 8 + s];
                U[r][v] = u;
            }
        }
        // column pass + quantize; qdct to global, packed shorts to registers
        double rinv = 1.0 / ((ch == 0) ? sy : sc);
        const double* rqt = (ch == 0) ? A.rqY : A.rqC;
        size_t qbase = (((size_t)b * 3 + ch) * NB + (size_t)(i * 64 + j)) * 64;
        int qp[32];                                  // 64 coeffs, 2 per int
        #pragma unroll
        for (int u = 0; u < 8; ++u) {
            alignas(16) float orow[8];
            #pragma unroll
            for (int v = 0; v < 8; ++v) {
                float d = 0.0f;
                #pragma unroll
                for (int r = 0; r < 8; ++r) d += A.Cf[u * 8 + r] * U[r][v];
                orow[v] = (float)rint((double)d * (rqt[u * 8 + v] * rinv));
            }
            *(float4*)(out + qbase + u * 8)     = ((float4*)orow)[0];
            *(float4*)(out + qbase + u * 8 + 4) = ((float4*)orow)[1];
            #pragma unroll
            for (int h = 0; h < 4; ++h) {
                int s0 = (int)orow[2 * h], s1 = (int)orow[2 * h + 1];
                qp[u * 4 + h] = (s0 & 0xffff) | (int)(((unsigned)s1) << 16);
            }
        }
        // previous block's coeffs (lane j-1); j==0 rows repaired by k_fix
        int pp[32];
        #pragma unroll
        for (int w = 0; w < 32; ++w) pp[w] = __shfl_up(qp[w], 1, 64);
        // blocks = log2(|delta(zigzag)| + 1), all from registers
        size_t bbase = (size_t)QD + qbase;
        #pragma unroll
        for (int g = 0; g < 16; ++g) {
            alignas(16) float bo[4];
            #pragma unroll
            for (int q = 0; q < 4; ++q) {
                constexpr int dummy = 0; (void)dummy;
                int m = ZZc[g * 4 + q];
                int cu = (m & 1) ? (qp[m >> 1] >> 16) : ((qp[m >> 1] << 16) >> 16);
                int pv = (m & 1) ? (pp[m >> 1] >> 16) : ((pp[m >> 1] << 16) >> 16);
                bo[q] = log2f(fabsf((float)(cu - pv)) + 1.0f);
            }
            *(float4*)(out + bbase + g * 4) = ((float4*)bo)[0];
        }
        // pixel maps: wave0 -> enc_qf, wave1 -> enc_scale (verbatim R4)
        if (ch < 2) {
            float4 v4 = (ch == 0)
                ? make_float4((float)qy, (float)qc, (float)qy, (float)qc)
                : make_float4((float)sy, (float)sc, (float)sy, (float)sc);
            float* mbase = out + 2 * (size_t)QD + (ch ? PP : 0);
            size_t P = (size_t)(b * HH + i * 8) * WW + j * 8;   // float2 units
            #pragma unroll
            for (int rr = 0; rr < 8; ++rr) {
                float4* dst = (float4*)((float2*)mbase + P + (size_t)rr * WW);
                dst[0] = v4; dst[1] = v4; dst[2] = v4; dst[3] = v4;
            }
        }
    }
}

// Repair blocks-output rows where j==0 (prev block lives in another workgroup).
__global__ __launch_bounds__(256) void k_fix(const float* __restrict__ q,
                                             float* __restrict__ ob) {
    int idx = blockIdx.x * 256 + threadIdx.x;   // 32*3*64 rows * 64 coeffs
    int rid = idx >> 6, k = idx & 63;
    int bch = rid >> 6;
    int i = rid & 63;
    size_t base = ((size_t)bch * NB + (size_t)i * 64) * 64;
    int zk = c_zz[k];
    float cur = q[base + zk];
    float prv = (i > 0) ? q[base - 64 + zk] : 0.0f;
    ob[base + k] = log2f(fabsf(cur - prv) + 1.0f);
}

extern "C" void kernel_launch(void* const* d_in, const int* in_sizes, int n_in,
                              void* d_out, int out_size, void* d_ws, size_t ws_size,
                              hipStream_t stream) {
    const float* rgb = (const float*)d_in[0];
    float* out = (float*)d_out;
    double* ws = (double*)d_ws;                 // ~2.1 MB used (proven-safe range)
    double* ey = ws;
    double* ec = ws + (size_t)BB * NB;
    double* mm = ws + 2 * (size_t)BB * NB;

    static const double YQ[64] = {
        16,11,10,16,24,40,51,61, 12,12,14,19,26,58,60,55, 14,13,16,24,40,57,69,56,
        14,17,22,29,51,87,80,62, 18,22,37,56,68,109,103,77, 24,36,55,64,81,104,113,92,
        49,64,78,87,103,121,120,101, 72,92,95,98,112,100,103,99};
    static const double CQ[64] = {
        17,18,24,47,99,99,99,99, 18,21,26,66,99,99,99,99, 24,26,56,99,99,99,99,99,
        47,66,99,99,99,99,99,99, 99,99,99,99,99,99,99,99, 99,99,99,99,99,99,99,99,
        99,99,99,99,99,99,99,99, 99,99,99,99,99,99,99,99};

    QArg qa;
    for (int k = 0; k < 8; ++k)
        for (int n = 0; n < 8; ++n) {
            double v = 0.5 * cos((2.0 * n + 1.0) * (double)k * M_PI / 16.0);
            if (k == 0) v *= 0.70710678118654752440;
            qa.Cf[k * 8 + n] = (float)v;          // reference casts DCT_M to fp32
        }
    for (int k = 0; k < 64; ++k) { qa.rqY[k] = 1.0 / YQ[k]; qa.rqC[k] = 1.0 / CQ[k]; }

    dim3 blk(256);
    k_energy<<<BB * 64, blk, 0, stream>>>(rgb, ey, ec);
    k_minmax<<<BB, blk, 0, stream>>>(ey, ec, mm, out + TAILOFF);
    k_quant<<<BB * 64, blk, 0, stream>>>(rgb, qa, ey, ec, mm, out);
    k_fix<<<(BB * 3 * 64 * 64) / 256, blk, 0, stream>>>(out, out + QD);
}

// Round 7
// 429.925 us; speedup vs baseline: 1.3952x; 1.3952x over previous
//
#include <hip/hip_runtime.h>
#include <math.h>

#define BB 32
#define HH 512
#define WW 512
#define NB 4096                      // 64*64 blocks per image
#define QD 25165824                  // 32*3*4096*64  (qdct elements)
#define PP 16777216                  // 32*512*512*2  (enc_qf elements)
#define TAILOFF (2 * (size_t)QD + 2 * (size_t)PP)  // 83886080

// compile-time zigzag (folds to literal register selects in unrolled loops)
constexpr int ZZc[64] = {
    0,1,8,16,9,2,3,10,17,24,32,25,18,11,4,5,12,19,26,33,40,48,41,34,27,20,13,6,
    7,14,21,28,35,42,49,56,57,50,43,36,29,22,15,23,30,37,44,51,58,59,52,45,38,31,
    39,46,53,60,61,54,47,55,62,63};
__constant__ int c_zz[64] = {
    0,1,8,16,9,2,3,10,17,24,32,25,18,11,4,5,12,19,26,33,40,48,41,34,27,20,13,6,
    7,14,21,28,35,42,49,56,57,50,43,36,29,22,15,23,30,37,44,51,58,59,52,45,38,31,
    39,46,53,60,61,54,47,55,62,63};

struct QArg { float Cf[64]; double rqY[64]; double rqC[64]; };

__device__ __forceinline__ double qf_from_rank(double r) {
    double q = rint(2.0 + r * 48.0 + 0.0);
    return fmin(fmax(q, 2.0), 50.0);
}
__device__ __forceinline__ double scale_from_qf(double qf) {
    double s = (qf < 50.0) ? (5000.0 / qf) : (200.0 - 2.0 * qf);
    return rint(s) / 100.0;
}

// Rounded YCbCr for 16 consecutive px of one row; identical fp64 rint math to R1-R6.
__device__ __forceinline__ void ycc16(const float* __restrict__ src, int p0,
                                      int* y, int* cb, int* cr) {
    float px[48];
    const float4* s4 = (const float4*)(src + (size_t)p0 * 3);
    #pragma unroll
    for (int k = 0; k < 12; ++k) ((float4*)px)[k] = s4[k];
    #pragma unroll
    for (int k = 0; k < 16; ++k) {
        double R = px[3 * k], G = px[3 * k + 1], Bv = px[3 * k + 2];
        y[k]  = (int)(rint(R * (double)0.299f     + G * (double)0.587f     + Bv * (double)0.114f)             - 128.0);
        cb[k] = (int)(rint(R * (double)-0.168736f + G * (double)-0.331264f + Bv * (double)0.5f       + 128.0) - 128.0);
        cr[k] = (int)(rint(R * (double)0.5f       + G * (double)-0.418688f + Bv * (double)-0.081312f + 128.0) - 128.0);
    }
}

// Energy via Parseval: sum d^2 == sum x^2 (orthonormal DCT), d00 == sum(x)/8.
__global__ __launch_bounds__(256, 4) void k_energy(const float* __restrict__ rgb,
                                                   double* __restrict__ ey,
                                                   double* __restrict__ ec) {
    __shared__ int4 part[3][8][32];
    __shared__ double ecomb[2][64];
    int b = blockIdx.x >> 6, i = blockIdx.x & 63, t = threadIdx.x;
    const float* src = rgb + (size_t)(b * HH + i * 8) * WW * 3;
    {
        int y[16], cb[16], cr[16];
        ycc16(src, t * 16, y, cb, cr);
        int s[3][2] = {{0,0},{0,0},{0,0}}, s2[3][2] = {{0,0},{0,0},{0,0}};
        #pragma unroll
        for (int k = 0; k < 16; ++k) {
            int h = k >> 3;
            s[0][h] += y[k];  s2[0][h] += y[k] * y[k];
            s[1][h] += cb[k]; s2[1][h] += cb[k] * cb[k];
            s[2][h] += cr[k]; s2[2][h] += cr[k] * cr[k];
        }
        int r0 = t >> 5, c = t & 31;
        #pragma unroll
        for (int ch = 0; ch < 3; ++ch)
            part[ch][r0][c] = make_int4(s[ch][0], s2[ch][0], s[ch][1], s2[ch][1]);
    }
    __syncthreads();
    int ch = t >> 6, j = t & 63;
    if (ch < 3) {
        int S = 0, S2 = 0;
        #pragma unroll
        for (int r = 0; r < 8; ++r) {
            const int2* p = (const int2*)&part[ch][r][j >> 1];
            int2 v = p[j & 1];
            S += v.x; S2 += v.y;
        }
        double e = log1p((double)S2 - (double)S * (double)S * (1.0 / 64.0) + 1e-6);
        if (ch == 0) ey[b * NB + i * 64 + j] = e;
        else ecomb[ch - 1][j] = e;
    }
    __syncthreads();
    if (t < 64) ec[b * NB + i * 64 + t] = 0.5 * (ecomb[0][t] + ecomb[1][t]);
}

__global__ __launch_bounds__(256) void k_minmax(const double* __restrict__ ey,
                                                const double* __restrict__ ec,
                                                double* __restrict__ mm,
                                                float* __restrict__ out_tail) {
    __shared__ double s0[256], s1[256], s2[256], s3[256];
    int b = blockIdx.x, tid = threadIdx.x;
    double mny = 1e300, mxy = -1e300, mnc = 1e300, mxc = -1e300;
    for (int n = tid; n < NB; n += 256) {
        double vy = ey[b * NB + n], vc = ec[b * NB + n];
        mny = fmin(mny, vy); mxy = fmax(mxy, vy);
        mnc = fmin(mnc, vc); mxc = fmax(mxc, vc);
    }
    s0[tid] = mny; s1[tid] = mxy; s2[tid] = mnc; s3[tid] = mxc;
    __syncthreads();
    for (int off = 128; off > 0; off >>= 1) {
        if (tid < off) {
            s0[tid] = fmin(s0[tid], s0[tid + off]);
            s1[tid] = fmax(s1[tid], s1[tid + off]);
            s2[tid] = fmin(s2[tid], s2[tid + off]);
            s3[tid] = fmax(s3[tid], s3[tid + off]);
        }
        __syncthreads();
    }
    if (tid == 0) {
        mm[b] = s0[0]; mm[32 + b] = s1[0]; mm[64 + b] = s2[0]; mm[96 + b] = s3[0];
        double ry = (s1[0] - s0[0]) / (s1[0] - s0[0] + 1e-6);
        double rc = (s3[0] - s2[0]) / (s3[0] - s2[0] + 1e-6);
        out_tail[b]      = (float)qf_from_rank(0.0);
        out_tail[32 + b] = (float)qf_from_rank(ry);
        out_tail[64 + b] = (float)qf_from_rank(0.0);
        out_tail[96 + b] = (float)qf_from_rank(rc);
    }
}

// Compute as R6 (bit-identical), but ALL outputs stream through LDS so every
// global store is lane-coalesced full-line:
//   sqA = quantized shorts (natural order)  -> writer A (qdct floats)
//   sqB = zigzag-delta shorts (reg permute) -> writer B (log2 blocks)
__global__ __launch_bounds__(256, 3) void k_quant(const float* __restrict__ rgb,
                                                  QArg A,
                                                  const double* __restrict__ ey,
                                                  const double* __restrict__ ec,
                                                  const double* __restrict__ mm,
                                                  float* __restrict__ out) {
    __shared__ __align__(16) char lds[53248];
    short* sqA = (short*)lds;                    // [192][68] shorts, 26112 B
    short* sqB = (short*)(lds + 26112);          // [192][68] shorts, 26112 B
    float4* qsc = (float4*)(lds + 52224);        // [64] {qy,qc,sy,sc}
    short* planes = (short*)lds;                 // overlay; dead after S2

    int b = blockIdx.x >> 6, i = blockIdx.x & 63, t = threadIdx.x;
    {   // stage rounded ycc as int16 planes [3][8][512]
        int y[16], cb[16], cr[16];
        ycc16(rgb + (size_t)(b * HH + i * 8) * WW * 3, t * 16, y, cb, cr);
        alignas(16) short yb[16], cbb[16], crb[16];
        #pragma unroll
        for (int k = 0; k < 16; ++k) {
            yb[k] = (short)y[k]; cbb[k] = (short)cb[k]; crb[k] = (short)cr[k];
        }
        int4* d0 = (int4*)&planes[0 * 4096 + 16 * t];
        int4* d1 = (int4*)&planes[1 * 4096 + 16 * t];
        int4* d2 = (int4*)&planes[2 * 4096 + 16 * t];
        d0[0] = ((int4*)yb)[0];  d0[1] = ((int4*)yb)[1];
        d1[0] = ((int4*)cbb)[0]; d1[1] = ((int4*)cbb)[1];
        d2[0] = ((int4*)crb)[0]; d2[1] = ((int4*)crb)[1];
    }
    __syncthreads();                                       // S1
    int ch = t >> 6, j = t & 63;
    float U[8][8];
    double qy = 0, qc = 0, sy = 1, sc = 1;
    if (ch < 3) {
        // decision math (fp64, identical to R1-R6)
        int gt = b * NB + i * 64 + j;
        double eyv = ey[gt], ecv = ec[gt];
        double mny = mm[b], mxy = mm[32 + b], mnc = mm[64 + b], mxc = mm[96 + b];
        double ry = (eyv - mny) / (mxy - mny + 1e-6);
        double rc = (ecv - mnc) / (mxc - mnc + 1e-6);
        qy = qf_from_rank(ry); qc = qf_from_rank(rc);
        sy = scale_from_qf(qy); sc = scale_from_qf(qc);
        // fp32 DCT row pass (reads planes)
        #pragma unroll
        for (int r = 0; r < 8; ++r) {
            alignas(16) short xs[8];
            *(int4*)xs = *(const int4*)&planes[ch * 4096 + r * 512 + j * 8];
            float xr[8];
            #pragma unroll
            for (int s = 0; s < 8; ++s) xr[s] = (float)xs[s];
            #pragma unroll
            for (int v = 0; v < 8; ++v) {
                float u = 0.0f;
                #pragma unroll
                for (int s = 0; s < 8; ++s) u += xr[s] * A.Cf[v * 8 + s];
                U[r][v] = u;
            }
        }
    }
    __syncthreads();                                       // S2: planes dead
    if (ch < 3) {
        if (ch == 0) qsc[j] = make_float4((float)qy, (float)qc, (float)sy, (float)sc);
        double rinv = 1.0 / ((ch == 0) ? sy : sc);
        const double* rqt = (ch == 0) ? A.rqY : A.rqC;
        int row = (ch * 64 + j) * 68;
        int qp[32];                                        // 64 coeffs packed
        #pragma unroll
        for (int u = 0; u < 8; ++u) {
            alignas(8) short srow[8];
            #pragma unroll
            for (int v = 0; v < 8; ++v) {
                float dq = (float)rint([&]{
                    float d = 0.0f;
                    #pragma unroll
                    for (int r = 0; r < 8; ++r) d += A.Cf[u * 8 + r] * U[r][v];
                    return (double)d * (rqt[u * 8 + v] * rinv);
                }());
                srow[v] = (short)(int)dq;
            }
            ((long long*)&sqA[row + u * 8])[0] = ((long long*)srow)[0];
            ((long long*)&sqA[row + u * 8 + 4])[0] = ((long long*)srow)[1];
            #pragma unroll
            for (int h = 0; h < 4; ++h)
                qp[u * 4 + h] = ((int)srow[2 * h] & 0xffff) |
                                ((int)((unsigned)(int)srow[2 * h + 1] << 16));
        }
        int pp[32];
        #pragma unroll
        for (int w = 0; w < 32; ++w) pp[w] = __shfl_up(qp[w], 1, 64);
        // zigzag delta, permuted in registers (compile-time indices)
        #pragma unroll
        for (int g = 0; g < 8; ++g) {
            alignas(8) short dz[8];
            #pragma unroll
            for (int e = 0; e < 8; ++e) {
                int m = ZZc[g * 8 + e];
                int w = m >> 1;
                int cu = (m & 1) ? (qp[w] >> 16) : ((qp[w] << 16) >> 16);
                int pv = (m & 1) ? (pp[w] >> 16) : ((pp[w] << 16) >> 16);
                dz[e] = (short)(cu - pv);                  // j==0 fixed by k_fix
            }
            ((long long*)&sqB[row + g * 8])[0] = ((long long*)dz)[0];
            ((long long*)&sqB[row + g * 8 + 4])[0] = ((long long*)dz)[1];
        }
    }
    __syncthreads();                                       // S3

    size_t obase = ((size_t)b * 3 * NB + (size_t)i * 64) * 64;
    // writer A: qdct, contiguous float4 stream
    #pragma unroll
    for (int it = 0; it < 12; ++it) {
        int m = it * 256 + t;
        int mch = m >> 10, f = m & 1023;
        int mj = f >> 4, k4 = (f & 15) * 4;
        alignas(8) short s4[4];
        *(long long*)s4 = *(const long long*)&sqA[(mch * 64 + mj) * 68 + k4];
        float4 v = make_float4((float)s4[0], (float)s4[1], (float)s4[2], (float)s4[3]);
        *(float4*)(out + obase + (size_t)mch * NB * 64 + (size_t)mj * 64 + k4) = v;
    }
    // writer B: blocks, contiguous float4 stream
    #pragma unroll
    for (int it = 0; it < 12; ++it) {
        int m = it * 256 + t;
        int mch = m >> 10, f = m & 1023;
        int mj = f >> 4, k4 = (f & 15) * 4;
        alignas(8) short d4[4];
        *(long long*)d4 = *(const long long*)&sqB[(mch * 64 + mj) * 68 + k4];
        float4 v = make_float4(log2f(fabsf((float)d4[0]) + 1.0f),
                               log2f(fabsf((float)d4[1]) + 1.0f),
                               log2f(fabsf((float)d4[2]) + 1.0f),
                               log2f(fabsf((float)d4[3]) + 1.0f));
        *(float4*)(out + QD + obase + (size_t)mch * NB * 64 + (size_t)mj * 64 + k4) = v;
    }
    // writer C: pixel maps, contiguous float4 rows
    {
        float4 qs = qsc[t >> 2];
        float4 qv = make_float4(qs.x, qs.y, qs.x, qs.y);
        float4 sv = make_float4(qs.z, qs.w, qs.z, qs.w);
        float2* mq = (float2*)(out + 2 * (size_t)QD);
        float2* ms = (float2*)(out + 2 * (size_t)QD + PP);
        #pragma unroll
        for (int rr = 0; rr < 8; ++rr) {
            size_t P = ((size_t)(b * HH + i * 8 + rr)) * WW;
            ((float4*)(mq + P))[t] = qv;
            ((float4*)(ms + P))[t] = sv;
        }
    }
}

// Repair blocks-output rows where j==0 (prev block lives in another lane/WG).
__global__ __launch_bounds__(256) void k_fix(const float* __restrict__ q,
                                             float* __restrict__ ob) {
    int idx = blockIdx.x * 256 + threadIdx.x;   // 32*3*64 rows * 64 coeffs
    int rid = idx >> 6, k = idx & 63;
    int bch = rid >> 6;
    int i = rid & 63;
    size_t base = ((size_t)bch * NB + (size_t)i * 64) * 64;
    int zk = c_zz[k];
    float cur = q[base + zk];
    float prv = (i > 0) ? q[base - 64 + zk] : 0.0f;
    ob[base + k] = log2f(fabsf(cur - prv) + 1.0f);
}

extern "C" void kernel_launch(void* const* d_in, const int* in_sizes, int n_in,
                              void* d_out, int out_size, void* d_ws, size_t ws_size,
                              hipStream_t stream) {
    const float* rgb = (const float*)d_in[0];
    float* out = (float*)d_out;
    double* ws = (double*)d_ws;                 // ~2.1 MB used
    double* ey = ws;
    double* ec = ws + (size_t)BB * NB;
    double* mm = ws + 2 * (size_t)BB * NB;

    static const double YQ[64] = {
        16,11,10,16,24,40,51,61, 12,12,14,19,26,58,60,55, 14,13,16,24,40,57,69,56,
        14,17,22,29,51,87,80,62, 18,22,37,56,68,109,103,77, 24,36,55,64,81,104,113,92,
        49,64,78,87,103,121,120,101, 72,92,95,98,112,100,103,99};
    static const double CQ[64] = {
        17,18,24,47,99,99,99,99, 18,21,26,66,99,99,99,99, 24,26,56,99,99,99,99,99,
        47,66,99,99,99,99,99,99, 99,99,99,99,99,99,99,99, 99,99,99,99,99,99,99,99,
        99,99,99,99,99,99,99,99, 99,99,99,99,99,99,99,99};

    QArg qa;
    for (int k = 0; k < 8; ++k)
        for (int n = 0; n < 8; ++n) {
            double v = 0.5 * cos((2.0 * n + 1.0) * (double)k * M_PI / 16.0);
            if (k == 0) v *= 0.70710678118654752440;
            qa.Cf[k * 8 + n] = (float)v;          // reference casts DCT_M to fp32
        }
    for (int k = 0; k < 64; ++k) { qa.rqY[k] = 1.0 / YQ[k]; qa.rqC[k] = 1.0 / CQ[k]; }

    dim3 blk(256);
    k_energy<<<BB * 64, blk, 0, stream>>>(rgb, ey, ec);
    k_minmax<<<BB, blk, 0, stream>>>(ey, ec, mm, out + TAILOFF);
    k_quant<<<BB * 64, blk, 0, stream>>>(rgb, qa, ey, ec, mm, out);
    k_fix<<<(BB * 3 * 64 * 64) / 256, blk, 0, stream>>>(out, out + QD);
}